// Round 12
// baseline (290.251 us; speedup 1.0000x reference)
//
#include <hip/hip_runtime.h>
#include <hip/hip_fp16.h>

// Problem constants (B=4, S=8192, IN=OUT=1024, GROUP=128)
#define K_DIM 1024
#define N_DIM 1024

typedef int v4i __attribute__((ext_vector_type(4)));

__device__ __forceinline__ void async_load16(const void* g, void* l) {
    __builtin_amdgcn_global_load_lds(
        (const __attribute__((address_space(1))) unsigned int*)g,
        (__attribute__((address_space(3))) unsigned int*)l,
        16, 0, 0);
}

// Raw barrier: no compiler-forced vmcnt(0) drain. "memory" clobbers pin
// LDS/global *instructions* (completion is handled by explicit waitcnts).
#define BAR() do { asm volatile("" ::: "memory"); \
                   __builtin_amdgcn_s_barrier();  \
                   asm volatile("" ::: "memory"); } while (0)

// ---------------- Kernel A: fused weight prep + activation quant -----------
// Blocks [0,256): prep_w. Blocks [256, 256+8192): quant_x. Unchanged (R4).
__global__ __launch_bounds__(256) void prep_quant(const float* __restrict__ w,
                                                  const float* __restrict__ x,
                                                  signed char* __restrict__ wq,
                                                  float* __restrict__ wscale,
                                                  signed char* __restrict__ xq,
                                                  float* __restrict__ xs) {
    const int lane = threadIdx.x & 63;
    if (blockIdx.x < 256) {
        const int row = blockIdx.x * 4 + (threadIdx.x >> 6);
        const float4* wr = (const float4*)(w + (size_t)row * K_DIM);
        float4 v[4];
#pragma unroll
        for (int j = 0; j < 4; ++j) v[j] = wr[lane * 4 + j];

        float g = 0.f;
#pragma unroll
        for (int j = 0; j < 4; ++j) {
            g = fmaxf(g, fabsf(v[j].x)); g = fmaxf(g, fabsf(v[j].y));
            g = fmaxf(g, fabsf(v[j].z)); g = fmaxf(g, fabsf(v[j].w));
        }
        g = fmaxf(g, __shfl_xor(g, 1, 64));
        g = fmaxf(g, __shfl_xor(g, 2, 64));
        g = fmaxf(g, __shfl_xor(g, 4, 64));
        const float s = __half2float(__float2half(fmaxf(g, 1e-8f)));
        float t = s;
        t += __shfl_xor(t, 8, 64);
        t += __shfl_xor(t, 16, 64);
        t += __shfl_xor(t, 32, 64);
        if (lane == 0) wscale[row] = t * 0.125f;

        int pk[4];
#pragma unroll
        for (int j = 0; j < 4; ++j) {
            const int b0 = (v[j].x > 0.f) ? 1 : -1;
            const int b1 = (v[j].y > 0.f) ? 1 : -1;
            const int b2 = (v[j].z > 0.f) ? 1 : -1;
            const int b3 = (v[j].w > 0.f) ? 1 : -1;
            pk[j] = (b0 & 255) | ((b1 & 255) << 8) | ((b2 & 255) << 16) | (b3 << 24);
        }
        *(int4*)(wq + (size_t)row * K_DIM + lane * 16) = make_int4(pk[0], pk[1], pk[2], pk[3]);
    } else {
        const int row = (blockIdx.x - 256) * 4 + (threadIdx.x >> 6);
        const float4* xr = (const float4*)(x + (size_t)row * K_DIM);
        float4 v[4];
#pragma unroll
        for (int j = 0; j < 4; ++j) v[j] = xr[lane * 4 + j];

        float am = 0.f;
#pragma unroll
        for (int j = 0; j < 4; ++j) {
            am = fmaxf(am, fabsf(v[j].x)); am = fmaxf(am, fabsf(v[j].y));
            am = fmaxf(am, fabsf(v[j].z)); am = fmaxf(am, fabsf(v[j].w));
        }
#pragma unroll
        for (int off = 32; off >= 1; off >>= 1) am = fmaxf(am, __shfl_xor(am, off, 64));
        const float scale = fmaxf(am, 1e-8f) / 127.f;
        const float inv   = 1.0f / scale;   // wave-uniform, one divide

        int pk[4];
#pragma unroll
        for (int j = 0; j < 4; ++j) {
            const int b0 = (int)fminf(fmaxf(rintf(v[j].x * inv), -128.f), 127.f);
            const int b1 = (int)fminf(fmaxf(rintf(v[j].y * inv), -128.f), 127.f);
            const int b2 = (int)fminf(fmaxf(rintf(v[j].z * inv), -128.f), 127.f);
            const int b3 = (int)fminf(fmaxf(rintf(v[j].w * inv), -128.f), 127.f);
            pk[j] = (b0 & 255) | ((b1 & 255) << 8) | ((b2 & 255) << 16) | (b3 << 24);
        }
        *(int4*)(xq + (size_t)row * K_DIM + lane * 16) = make_int4(pk[0], pk[1], pk[2], pk[3]);
        if (lane == 0) xs[row] = scale;
    }
}

// ---------------- Kernel B: int8 GEMM, FAT K-step (BK=128) -----------------
// Model from 11 rounds: wall = slots x (MFMA/step + F), F ~ 4000 cy fixed
// per step (latency/serialization; invariant to barriers/occupancy/LDS
// traffic). This kernel halves slots and doubles per-step MFMA:
//   256x256 tile, BK=128, 8 K-tiles; 512 thr = 8 waves (2M x 4N), wave out
//   128x64 = acc[8][4]; per tile per wave: 2 K-64 slices x 32 MFMA = 64 MFMA
//   (2612 cy/SIMD at 2 waves/SIMD) vs R4's 1306.
// Predicted: 16 sequential slots x (2612 + F) ~ 44 us vs R4's 71.
// Schedule = R4's proven shape per tile: vmcnt(0) [staged a full fat phase
// ago] -> BAR -> STAGE(t+1, other buf; 8 calls x 8 KB) -> compute (2 slices)
// -> sched_barrier(0) -> lgkmcnt(0)  (rule #18; protects buffer overwrite).
// LDS: 2 bufs x (A 256x128 + B 256x128) = 128 KiB (dynamic), 1 block/CU.
// Swizzle (128-B rows, 8 x 16B chunks): LDS[row][p] = logical chunk p^(row&7)
// -- applied on the GLOBAL source of global_load_lds (dest linear tid*16, HW
// rule m104) and on ds_read addresses (rule #21). Frag reads: 16 lanes (r16)
// spread 2-per-chunk across all 8 chunks = 2-way = free (m136).
__global__ __launch_bounds__(512, 2) void gemm_i8(const signed char* __restrict__ A,
                                                  const signed char* __restrict__ Bw,
                                                  const float* __restrict__ xs,
                                                  const float* __restrict__ wscale,
                                                  const float* __restrict__ bias,
                                                  float* __restrict__ out) {
    extern __shared__ __align__(16) signed char lds[];   // [2][A 32K | B 32K]

    const int tid  = threadIdx.x;
    const int lane = tid & 63;
    const int wave = tid >> 6;    // 0..7
    const int wm   = wave >> 2;   // 0..1  (128-row half)
    const int wn   = wave & 3;    // 0..3  (64-col quarter)

    // XCD mapping: xcd = bid&7 owns 16 mT x 4 nT; A-panel lands in one XCD's
    // L2 and is reused by its 4 n-blocks; wq (1 MB) L2-resident everywhere.
    const int bid = blockIdx.x;           // 512 blocks
    const int xcd = bid & 7;
    const int u   = bid >> 3;             // 0..63
    const int mT  = xcd * 16 + (u >> 2);  // 0..127
    const int nT  = u & 3;                // 0..3
    const size_t mBase = (size_t)mT * 256;
    const int    nBase = nT * 256;

    // staging: one call = 512 thr x 16B = 8 KB = 64 rows x 128 B.
    // row = tid>>3 (+64c per call), phys chunk = tid&7,
    // source chunk = (tid&7) ^ (row&7)  [64 = 0 mod 8 -> same scol all calls].
    const int srow = tid >> 3;                          // 0..63
    const int scol = ((tid & 7) ^ (srow & 7)) * 16;     // inverse-swizzled col
    const int dst  = tid * 16;                          // linear LDS dest
    const signed char* Ag = A  + (mBase + srow) * K_DIM + scol;
    const signed char* Bg = Bw + (size_t)(nBase + srow) * K_DIM + scol;

    // STAGE one K-tile (BK=128): A rows 0..255 (4 calls) + B rows (4 calls)
#define STAGE(b, kt) do {                                                     \
        const int _ko = (kt) * 128;                                           \
        const int _bb = (b) * 65536;                                          \
        async_load16(Ag + _ko,                       lds + _bb +         dst);\
        async_load16(Ag + (size_t) 64 * K_DIM + _ko, lds + _bb +  8192 + dst);\
        async_load16(Ag + (size_t)128 * K_DIM + _ko, lds + _bb + 16384 + dst);\
        async_load16(Ag + (size_t)192 * K_DIM + _ko, lds + _bb + 24576 + dst);\
        async_load16(Bg + _ko,                       lds + _bb + 32768 + dst);\
        async_load16(Bg + (size_t) 64 * K_DIM + _ko, lds + _bb + 40960 + dst);\
        async_load16(Bg + (size_t)128 * K_DIM + _ko, lds + _bb + 49152 + dst);\
        async_load16(Bg + (size_t)192 * K_DIM + _ko, lds + _bb + 57344 + dst);\
    } while (0)

    // fragment LDS offsets. Row byte-stride 128. Slice ks (0/1): logical
    // chunk = ks*4+g -> phys = (ks*4+g)^(r16&7); byte = phys*16.
    // (c^4)*16 == (c*16)^64 -> slice-1 offset = slice-0 offset ^ 64.
    const int r16 = lane & 15;
    const int g   = lane >> 4;                        // 16B chunk within K-64
    const int c0  = ((g ^ (r16 & 7)) * 16);           // slice-0 phys byte
    int aoff[8], boff[4];
#pragma unroll
    for (int mf = 0; mf < 8; ++mf)
        aoff[mf] = (wm * 128 + mf * 16 + r16) * 128 + c0;
#pragma unroll
    for (int nf = 0; nf < 4; ++nf)
        boff[nf] = 32768 + (wn * 64 + nf * 16 + r16) * 128 + c0;

    v4i acc[8][4] = {};

    STAGE(0, 0);   // prologue: tile 0 in flight; waited at t=0 top

    for (int t = 0; t < 8; ++t) {
        // tile t's 8 calls are the only outstanding VMEM ops; issued one full
        // fat compute phase (~2600+ cy) ago (prologue for t=0).
        asm volatile("s_waitcnt vmcnt(0)" ::: "memory");
        BAR();
        if (t < 7) STAGE((t + 1) & 1, t + 1);   // overwrite buf last read t-1

        const signed char* Lb = lds + (t & 1) * 65536;

#pragma unroll
        for (int ks = 0; ks < 2; ++ks) {
            const int sx = ks * 64;   // phys byte offset flip for slice 1
            v4i af[8], bf[4];
#pragma unroll
            for (int mf = 0; mf < 8; ++mf)
                af[mf] = *(const v4i*)(Lb + (aoff[mf] ^ sx));
#pragma unroll
            for (int nf = 0; nf < 4; ++nf)
                bf[nf] = *(const v4i*)(Lb + (boff[nf] ^ sx));
#pragma unroll
            for (int mf = 0; mf < 8; ++mf)
#pragma unroll
                for (int nf = 0; nf < 4; ++nf)
                    acc[mf][nf] = __builtin_amdgcn_mfma_i32_16x16x64_i8(
                        af[mf], bf[nf], acc[mf][nf], 0, 0, 0);
        }

        // pin instruction order (rule #18), then require this wave's ds_reads
        // complete before it can cross the next barrier (after which staging
        // overwrites the other buffer).
        __builtin_amdgcn_sched_barrier(0);
        asm volatile("s_waitcnt lgkmcnt(0)" ::: "memory");
    }
#undef STAGE

    // epilogue: C/D layout col = lane&15, row = (lane>>4)*4 + reg
    const int rq = g * 4;
    float xsr[8][4];
#pragma unroll
    for (int mf = 0; mf < 8; ++mf)
#pragma unroll
        for (int i = 0; i < 4; ++i)
            xsr[mf][i] = xs[mBase + wm * 128 + mf * 16 + rq + i];

#pragma unroll
    for (int nf = 0; nf < 4; ++nf) {
        const int col   = nBase + wn * 64 + nf * 16 + r16;
        const float wsc = wscale[col];
        const float bb  = bias[col];
#pragma unroll
        for (int mf = 0; mf < 8; ++mf) {
#pragma unroll
            for (int i = 0; i < 4; ++i) {
                const size_t row = mBase + wm * 128 + mf * 16 + rq + i;
                out[row * N_DIM + col] = (float)acc[mf][nf][i] * xsr[mf][i] * wsc + bb;
            }
        }
    }
}

extern "C" void kernel_launch(void* const* d_in, const int* in_sizes, int n_in,
                              void* d_out, int out_size, void* d_ws, size_t ws_size,
                              hipStream_t stream) {
    const float* x    = (const float*)d_in[0];
    const float* w    = (const float*)d_in[1];
    const float* bias = (const float*)d_in[2];
    float* out = (float*)d_out;

    const int BT = in_sizes[0] / K_DIM;  // 32768 tokens

    // workspace carve
    char* ws = (char*)d_ws;
    signed char* xq     = (signed char*)ws;                                          // BT*1024 B
    float*       xs     = (float*)(ws + (size_t)BT * K_DIM);                         // BT*4 B
    signed char* wq     = (signed char*)(ws + (size_t)BT * K_DIM + (size_t)BT * 4);  // 1 MB
    float*       wscale = (float*)((char*)wq + (size_t)N_DIM * K_DIM);               // 4 KB

    static bool s_attr_set = false;
    if (!s_attr_set) {
        hipFuncSetAttribute((const void*)gemm_i8,
                            hipFuncAttributeMaxDynamicSharedMemorySize, 131072);
        s_attr_set = true;
    }

    prep_quant<<<256 + BT / 4, 256, 0, stream>>>(w, x, wq, wscale, xq, xs);
    gemm_i8<<<(BT / 256) * (N_DIM / 256), 512, 131072, stream>>>(xq, wq, xs, wscale, bias, out);
}